// Round 2
// baseline (680.005 us; speedup 1.0000x reference)
//
#include <hip/hip_runtime.h>

typedef unsigned short u16;
typedef unsigned int   u32;
typedef __bf16 bf16x8 __attribute__((ext_vector_type(8)));
typedef float  f32x4  __attribute__((ext_vector_type(4)));
typedef float  f32x2  __attribute__((ext_vector_type(2)));
typedef unsigned short u16x8 __attribute__((ext_vector_type(8)));
typedef unsigned int   u32x2 __attribute__((ext_vector_type(2)));

#define PPB 128   // pairs per chunk (8 m-tiles) -> gather = exactly 1 unit/thread
#define CPB 5     // chunks per block (software pipeline depth)

__device__ __forceinline__ u16 f2bf(float f){
  union { float f; u32 i; } v; v.f = f;
  u32 u = v.i;
  u += 0x7fffu + ((u >> 16) & 1u);   // RNE (finite values only)
  return (u16)(u >> 16);
}
__device__ __forceinline__ float tanh_fast(float x){
  x = fminf(fmaxf(x, -12.f), 12.f);
  float t = __builtin_amdgcn_exp2f(x * 2.885390081777926815f); // e^{2x}
  return (t - 1.f) * __builtin_amdgcn_rcpf(t + 1.f);
}

// ------- transpose+downcast: in f32[R][C] -> out bf16[C][R]; R,C mult of 64
__global__ __launch_bounds__(256) void transpose_cast_k(
    const float* __restrict__ in, u16* __restrict__ out, int R, int C)
{
  __shared__ u16 tile[64][65];
  const int tx = threadIdx.x & 63;
  const int ty = threadIdx.x >> 6;        // 0..3
  const int c0 = blockIdx.x * 64;
  const int r0 = blockIdx.y * 64;
#pragma unroll
  for (int rr = 0; rr < 16; ++rr){
    int r = ty + rr * 4;
    tile[r][tx] = f2bf(in[(size_t)(r0 + r) * C + c0 + tx]);
  }
  __syncthreads();
#pragma unroll
  for (int rr = 0; rr < 16; ++rr){
    int r = ty + rr * 4;
    out[(size_t)(c0 + r) * R + r0 + tx] = tile[tx][r];
  }
}

// ------- W2 f32[256][512] -> w2b bf16[8][512][32]: w2b[kk][n][kl] = W2[kk*32+kl][n]
__global__ __launch_bounds__(256) void w2_block_k(
    const float* __restrict__ in, u16* __restrict__ out)
{
  __shared__ float tile[32][65];
  const int kk = blockIdx.x;       // 0..7
  const int n0 = blockIdx.y * 64;  // 0..448
  const int t  = threadIdx.x;
  {
    int r  = t >> 3;               // k-row 0..31
    int c8 = t & 7;                // 8-col group
    const float* src = in + (size_t)(kk*32 + r)*512 + n0 + c8*8;
    f32x4 v0 = *(const f32x4*)src;
    f32x4 v1 = *(const f32x4*)(src + 4);
#pragma unroll
    for (int e = 0; e < 4; ++e){
      tile[r][c8*8 + e]     = v0[e];
      tile[r][c8*8 + 4 + e] = v1[e];
    }
  }
  __syncthreads();
  {
    int c = t >> 2, part = t & 3;  // c: n within tile, part: 8-k group
    u16x8 o;
#pragma unroll
    for (int e = 0; e < 8; ++e) o[e] = f2bf(tile[part*8 + e][c]);
    *(u16x8*)(out + ((size_t)kk*512 + n0 + c)*32 + part*8) = o;
  }
}

// ---------------- fused PILayer kernel: 1024 thr, CPB-chunk software pipeline ----
// Chunk loop per block (CPB chunks of PPB=128 pairs). Per chunk:
//   P1: idx-loads(t+1) | read sh_inter[cur] -> GEMM1 -> tanh -> sh_h ; barrier
//   P2: p1-row-loads(t+1) | GEMM2 vs reg-resident W2 -> basis fold -> out
//       | convert+ds_write(t+1) into sh_inter[nxt] ; barrier ; swap
// Gather latency of chunk t+1 hides under chunk t's MFMA work (T14 split).
// sh_h [128][512B] uses physical_chunk = logical_chunk ^ (row&15) (16B chunks):
// conflict-free b128 reads in P2 and b64 writes in P1.
__global__ __launch_bounds__(1024, 4) void pilayer_kernel(
    const float* __restrict__ p1,     // [N_NODES][64] f32
    const int* __restrict__ pair_i,   // [NP]
    const int* __restrict__ pair_j,   // [NP]
    const float* __restrict__ basis,  // [NP][8] f32
    const u16* __restrict__ w1t,      // [256][64] bf16
    const u16* __restrict__ w2b,      // [8][512][32] bf16 (k-blocked W2^T)
    float* __restrict__ out,          // [NP][64] f32
    int n_pairs)
{
  extern __shared__ __align__(16) u16 smem[];
  u16* sh_h  = smem;                 // [128][256] swizzled = 65536 B
  u16* sh_i0 = smem + PPB * 256;     // [128][64]  swizzled = 16384 B
  u16* sh_i1 = sh_i0 + PPB * 64;     // [128][64]  swizzled = 16384 B

  const int tid  = threadIdx.x;
  const int blk  = blockIdx.x;
  const int lane = tid & 63;
  const int w    = tid >> 6;     // wave 0..15
  const int m16  = lane & 15;
  const int q    = lane >> 4;    // quad 0..3
  const int sw3  = m16 & 7;      // 3-bit row-XOR (sh_inter, 8 chunks/row)
  // sh_h chunk swizzle: 4-bit row-XOR (32 chunks/row)
  const int cw   = (w*2 + (q >> 1)) ^ m16;   // P1 write chunk

  // ---- Persistent W2 fragments (64 VGPR), issued first ----
  bf16x8 awf[8][2];
#pragma unroll
  for (int kk = 0; kk < 8; ++kk)
#pragma unroll
    for (int nt = 0; nt < 2; ++nt)
      awf[kk][nt] = *(const bf16x8*)(
          w2b + ((size_t)kk*512 + w*32 + nt*16 + m16)*32 + q*8);
  // ---- Persistent W1 fragments for P1 (8 VGPR) ----
  const u16* arow = w1t + (size_t)(w*16 + m16)*64 + q*8;
  bf16x8 af0 = *(const bf16x8*)(arow);
  bf16x8 af1 = *(const bf16x8*)(arow + 32);
  __builtin_amdgcn_sched_barrier(0);

  const int pbase = blk * CPB * PPB;   // first pair of this block
  const int m_g   = tid >> 3;          // gather row 0..127 (1 unit/thread)
  const int seg_g = tid & 7;           // 8-float segment 0..7

  // ---- Prologue: gather chunk 0 -> sh_i0 ----
  {
    int p = pbase + m_g;
    if (p >= n_pairs) p = n_pairs - 1;
    const float* si = p1 + (size_t)pair_i[p]*64 + seg_g*8;
    const float* sj = p1 + (size_t)pair_j[p]*64 + seg_g*8;
    f32x4 a0 = ((const f32x4*)si)[0], a1 = ((const f32x4*)si)[1];
    f32x4 b0 = ((const f32x4*)sj)[0], b1 = ((const f32x4*)sj)[1];
    u16x8 r;
#pragma unroll
    for (int e = 0; e < 4; ++e){
      r[e]     = f2bf(a0[e] + b0[e]);
      r[e + 4] = f2bf(a1[e] + b1[e]);
    }
    *(u16x8*)(sh_i0 + m_g*64 + ((seg_g ^ (m_g & 7)) * 8)) = r;
  }
  __syncthreads();

  u16* sin_cur = sh_i0;
  u16* sin_nxt = sh_i1;
  int nxt_i = 0, nxt_j = 0;

  for (int t = 0; t < CPB; ++t){
    const int pb = pbase + t * PPB;
    const bool pf = (t + 1 < CPB);

    // ---- P1: issue next-chunk index loads, then GEMM1 + tanh -> sh_h ----
    if (pf){
      int pn = pb + PPB + m_g;
      if (pn >= n_pairs) pn = n_pairs - 1;
      nxt_i = pair_i[pn];
      nxt_j = pair_j[pn];
      asm volatile("" : "+v"(nxt_i), "+v"(nxt_j));   // pin issue before P1 body
    }
    for (int mt1 = 0; mt1 < PPB/16; ++mt1){
      const u16* irow = sin_cur + (size_t)(mt1*16 + m16) * 64;
      bf16x8 b0 = *(const bf16x8*)(irow + ((q ^ sw3) * 8));
      bf16x8 b1 = *(const bf16x8*)(irow + (((q + 4) ^ sw3) * 8));
      f32x4 acc = {0.f, 0.f, 0.f, 0.f};
      acc = __builtin_amdgcn_mfma_f32_16x16x32_bf16(af0, b0, acc, 0, 0, 0);
      acc = __builtin_amdgcn_mfma_f32_16x16x32_bf16(af1, b1, acc, 0, 0, 0);
      u32 lo = (u32)f2bf(tanh_fast(acc[0])) | ((u32)f2bf(tanh_fast(acc[1])) << 16);
      u32 hi = (u32)f2bf(tanh_fast(acc[2])) | ((u32)f2bf(tanh_fast(acc[3])) << 16);
      u32x2 pk = {lo, hi};
      *(u32x2*)(sh_h + (size_t)(mt1*16 + m16)*256 + cw*8 + (q & 1)*4) = pk;
    }
    __syncthreads();

    // ---- P2: issue next-chunk p1-row loads (indices already arrived), ----
    // ---- GEMM2 vs register W2, basis fold, store; then stage t+1 to LDS ----
    f32x4 gi0, gi1, gj0, gj1;
    if (pf){
      const float* si = p1 + (size_t)(u32)nxt_i*64 + seg_g*8;
      const float* sj = p1 + (size_t)(u32)nxt_j*64 + seg_g*8;
      gi0 = ((const f32x4*)si)[0]; gi1 = ((const f32x4*)si)[1];
      gj0 = ((const f32x4*)sj)[0]; gj1 = ((const f32x4*)sj)[1];
      asm volatile("" : "+v"(gi0), "+v"(gi1), "+v"(gj0), "+v"(gj1)); // pin issue
    }

    for (int mt = 0; mt < PPB/16; ++mt){
      const int row = mt*16 + m16;
      const int mg  = pb + row;
      const int mgc = (mg < n_pairs) ? mg : (n_pairs - 1);
      f32x4 bb = *(const f32x4*)(basis + (size_t)mgc*8 + (q & 1)*4);

      const u16* hbase = sh_h + (size_t)row * 256;
      f32x4 acc0 = {0.f, 0.f, 0.f, 0.f};
      f32x4 acc1 = {0.f, 0.f, 0.f, 0.f};

      bf16x8 bh = *(const bf16x8*)(hbase + ((q ^ m16) * 8));   // chunk kk=0
#pragma unroll
      for (int kk = 0; kk < 8; ++kk){
        bf16x8 bhn;
        if (kk < 7) bhn = *(const bf16x8*)(hbase + ((((kk + 1)*4 + q) ^ m16) * 8));
        acc0 = __builtin_amdgcn_mfma_f32_16x16x32_bf16(awf[kk][0], bh, acc0, 0, 0, 0);
        acc1 = __builtin_amdgcn_mfma_f32_16x16x32_bf16(awf[kk][1], bh, acc1, 0, 0, 0);
        bh = bhn;
      }

      // n = w*32 + nt*16 + q*4 + reg; c = w*4 + nt*2 + (q>>1); b = (q&1)*4 + reg
#pragma unroll
      for (int nt = 0; nt < 2; ++nt){
        f32x4 a = (nt == 0) ? acc0 : acc1;
        float s = a[0]*bb[0] + a[1]*bb[1] + a[2]*bb[2] + a[3]*bb[3];
        s += __shfl_xor(s, 16);          // sum b-halves (q0+q1 / q2+q3)
        float v2 = __shfl_xor(s, 32);    // partner c-channel
        if (q == 0 && mg < n_pairs){
          f32x2 pk = {s, v2};
          *(f32x2*)(out + (size_t)mg*64 + w*4 + nt*2) = pk;
        }
      }
    }

    if (pf){   // convert + stage chunk t+1 into the other inter buffer
      u16x8 r;
#pragma unroll
      for (int e = 0; e < 4; ++e){
        r[e]     = f2bf(gi0[e] + gj0[e]);
        r[e + 4] = f2bf(gi1[e] + gj1[e]);
      }
      *(u16x8*)(sin_nxt + m_g*64 + ((seg_g ^ (m_g & 7)) * 8)) = r;
    }
    __syncthreads();
    u16* tmp = sin_cur; sin_cur = sin_nxt; sin_nxt = tmp;
  }
}

extern "C" void kernel_launch(void* const* d_in, const int* in_sizes, int n_in,
                              void* d_out, int out_size, void* d_ws, size_t ws_size,
                              hipStream_t stream)
{
  const float* p1    = (const float*)d_in[0];
  const int*   pi    = (const int*)d_in[1];
  const int*   pj    = (const int*)d_in[2];
  const float* basis = (const float*)d_in[3];
  const float* W1    = (const float*)d_in[4];  // [64][256] f32
  const float* W2    = (const float*)d_in[5];  // [256][512] f32
  float* out = (float*)d_out;

  u16* w1t = (u16*)d_ws;                   // [256][64]   bf16 = 32 KB
  u16* w2b = w1t + 64 * 256;               // [8][512][32] bf16 = 256 KB

  const int n_pairs = in_sizes[1];
  const int lds_bytes = (PPB * 256 + 2 * PPB * 64) * (int)sizeof(u16);  // 98304

  static int attr_done = 0;  // attribute is device-global state, not stream work;
  if (!attr_done){           // first (uncaptured) call sets it before capture
    hipFuncSetAttribute((const void*)pilayer_kernel,
                        hipFuncAttributeMaxDynamicSharedMemorySize, lds_bytes);
    attr_done = 1;
  }

  transpose_cast_k<<<dim3(4, 1), 256, 0, stream>>>(W1, w1t, 64, 256);
  w2_block_k<<<dim3(8, 8), 256, 0, stream>>>(W2, w2b);

  const int n_chunks = (n_pairs + PPB - 1) / PPB;
  const int blocks   = (n_chunks + CPB - 1) / CPB;
  pilayer_kernel<<<blocks, 1024, lds_bytes, stream>>>(
      p1, pi, pj, basis, w1t, w2b, out, n_pairs);
}

// Round 3
// 605.410 us; speedup vs baseline: 1.1232x; 1.1232x over previous
//
#include <hip/hip_runtime.h>

typedef unsigned short u16;
typedef unsigned int   u32;
typedef __bf16 bf16x8 __attribute__((ext_vector_type(8)));
typedef float  f32x4  __attribute__((ext_vector_type(4)));
typedef float  f32x2  __attribute__((ext_vector_type(2)));
typedef unsigned short u16x8 __attribute__((ext_vector_type(8)));
typedef unsigned int   u32x2 __attribute__((ext_vector_type(2)));

#define PPB 128   // pairs per chunk (8 m-tiles) -> gather = exactly 1 unit/thread
#define CPB 5     // chunks per block (software pipeline depth)

__device__ __forceinline__ u16 f2bf(float f){
  union { float f; u32 i; } v; v.f = f;
  u32 u = v.i;
  u += 0x7fffu + ((u >> 16) & 1u);   // RNE (finite values only)
  return (u16)(u >> 16);
}
__device__ __forceinline__ float tanh_fast(float x){
  x = fminf(fmaxf(x, -12.f), 12.f);
  float t = __builtin_amdgcn_exp2f(x * 2.885390081777926815f); // e^{2x}
  return (t - 1.f) * __builtin_amdgcn_rcpf(t + 1.f);
}

// ------- transpose+downcast: in f32[R][C] -> out bf16[C][R]; R,C mult of 64
__global__ __launch_bounds__(256) void transpose_cast_k(
    const float* __restrict__ in, u16* __restrict__ out, int R, int C)
{
  __shared__ u16 tile[64][65];
  const int tx = threadIdx.x & 63;
  const int ty = threadIdx.x >> 6;        // 0..3
  const int c0 = blockIdx.x * 64;
  const int r0 = blockIdx.y * 64;
#pragma unroll
  for (int rr = 0; rr < 16; ++rr){
    int r = ty + rr * 4;
    tile[r][tx] = f2bf(in[(size_t)(r0 + r) * C + c0 + tx]);
  }
  __syncthreads();
#pragma unroll
  for (int rr = 0; rr < 16; ++rr){
    int r = ty + rr * 4;
    out[(size_t)(c0 + r) * R + r0 + tx] = tile[tx][r];
  }
}

// ------- W2 f32[256][512] -> w2b bf16[8][512][32]: w2b[kk][n][kl] = W2[kk*32+kl][n]
__global__ __launch_bounds__(256) void w2_block_k(
    const float* __restrict__ in, u16* __restrict__ out)
{
  __shared__ float tile[32][65];
  const int kk = blockIdx.x;       // 0..7
  const int n0 = blockIdx.y * 64;  // 0..448
  const int t  = threadIdx.x;
  {
    int r  = t >> 3;               // k-row 0..31
    int c8 = t & 7;                // 8-col group
    const float* src = in + (size_t)(kk*32 + r)*512 + n0 + c8*8;
    f32x4 v0 = *(const f32x4*)src;
    f32x4 v1 = *(const f32x4*)(src + 4);
#pragma unroll
    for (int e = 0; e < 4; ++e){
      tile[r][c8*8 + e]     = v0[e];
      tile[r][c8*8 + 4 + e] = v1[e];
    }
  }
  __syncthreads();
  {
    int c = t >> 2, part = t & 3;  // c: n within tile, part: 8-k group
    u16x8 o;
#pragma unroll
    for (int e = 0; e < 8; ++e) o[e] = f2bf(tile[part*8 + e][c]);
    *(u16x8*)(out + ((size_t)kk*512 + n0 + c)*32 + part*8) = o;
  }
}

// ---------------- fused PILayer kernel: 1024 thr, CPB-chunk software pipeline ----
// Per chunk t:
//   A: drain sh_out(t-1) -> global (full-line f32x4) | issue idx loads(t+1)
//      | GEMM1: sh_inter[cur] -> tanh -> sh_h ; barrier
//   B: issue p1-row loads(t+1) | GEMM2 vs reg W2 -> basis fold -> sh_out
//      | convert+ds_write(t+1) -> sh_inter[nxt] ; barrier ; swap
// Loads are issued early with sched_barrier(0) (ordering pin, NO value pin ->
// no forced vmcnt(0)); first use is ~a full GEMM phase later.
// Output staged in LDS so HBM writes are full 64B lines (kills the RFO/partial-
// eviction amplification seen in round 2: WRITE 590MB -> ~205MB expected).
__global__ __launch_bounds__(1024, 4) void pilayer_kernel(
    const float* __restrict__ p1,     // [N_NODES][64] f32
    const int* __restrict__ pair_i,   // [NP]
    const int* __restrict__ pair_j,   // [NP]
    const float* __restrict__ basis,  // [NP][8] f32
    const u16* __restrict__ w1t,      // [256][64] bf16
    const u16* __restrict__ w2b,      // [8][512][32] bf16 (k-blocked W2^T)
    float* __restrict__ out,          // [NP][64] f32
    int n_pairs)
{
  extern __shared__ __align__(16) u16 smem[];
  u16*   sh_h   = smem;                        // [128][256] swizzled = 65536 B
  u16*   sh_i0  = smem + PPB * 256;            // [128][64]  swizzled = 16384 B
  u16*   sh_i1  = sh_i0 + PPB * 64;            // [128][64]  swizzled = 16384 B
  float* sh_out = (float*)(sh_i1 + PPB * 64);  // [128][68] f32       = 34816 B

  const int tid  = threadIdx.x;
  const int blk  = blockIdx.x;
  const int lane = tid & 63;
  const int w    = tid >> 6;     // wave 0..15
  const int m16  = lane & 15;
  const int q    = lane >> 4;    // quad 0..3
  const int sw3  = m16 & 7;      // 3-bit row-XOR (sh_inter, 8 chunks/row)
  const int cw   = (w*2 + (q >> 1)) ^ m16;   // sh_h write chunk (4-bit row-XOR)

  // ---- Persistent W2 fragments (64 VGPR), issued first ----
  bf16x8 awf[8][2];
#pragma unroll
  for (int kk = 0; kk < 8; ++kk)
#pragma unroll
    for (int nt = 0; nt < 2; ++nt)
      awf[kk][nt] = *(const bf16x8*)(
          w2b + ((size_t)kk*512 + w*32 + nt*16 + m16)*32 + q*8);
  // ---- Persistent W1 fragments for P1 (8 VGPR) ----
  const u16* arow = w1t + (size_t)(w*16 + m16)*64 + q*8;
  bf16x8 af0 = *(const bf16x8*)(arow);
  bf16x8 af1 = *(const bf16x8*)(arow + 32);
  __builtin_amdgcn_sched_barrier(0);

  const int pbase = blk * CPB * PPB;   // first pair of this block
  const int m_g   = tid >> 3;          // gather/drain row 0..127
  const int seg_g = tid & 7;           // 8-float segment 0..7

  // ---- Prologue: gather chunk 0 -> sh_i0 ----
  {
    int p = pbase + m_g;
    if (p >= n_pairs) p = n_pairs - 1;
    const float* si = p1 + (size_t)pair_i[p]*64 + seg_g*8;
    const float* sj = p1 + (size_t)pair_j[p]*64 + seg_g*8;
    f32x4 a0 = ((const f32x4*)si)[0], a1 = ((const f32x4*)si)[1];
    f32x4 b0 = ((const f32x4*)sj)[0], b1 = ((const f32x4*)sj)[1];
    u16x8 r;
#pragma unroll
    for (int e = 0; e < 4; ++e){
      r[e]     = f2bf(a0[e] + b0[e]);
      r[e + 4] = f2bf(a1[e] + b1[e]);
    }
    *(u16x8*)(sh_i0 + m_g*64 + ((seg_g ^ (m_g & 7)) * 8)) = r;
  }
  __syncthreads();

  u16* sin_cur = sh_i0;
  u16* sin_nxt = sh_i1;
  int nxt_i = 0, nxt_j = 0;

  for (int t = 0; t < CPB; ++t){
    const int pb = pbase + t * PPB;
    const bool pf = (t + 1 < CPB);

    // ---- A: drain previous chunk's staged output as full-line stores ----
    if (t > 0){
      const int mg = pb - PPB + m_g;
      if (mg < n_pairs){
        const float* src = sh_out + m_g*68 + seg_g*8;
        f32x4 v0 = *(const f32x4*)(src);
        f32x4 v1 = *(const f32x4*)(src + 4);
        float* dst = out + (size_t)mg*64 + seg_g*8;
        *(f32x4*)(dst)     = v0;
        *(f32x4*)(dst + 4) = v1;
      }
    }
    // issue next-chunk index loads (first use: phase B top)
    if (pf){
      int pn = pb + PPB + m_g;
      if (pn >= n_pairs) pn = n_pairs - 1;
      nxt_i = pair_i[pn];
      nxt_j = pair_j[pn];
    }
    __builtin_amdgcn_sched_barrier(0);   // ordering pin only — no value pin

    // ---- A: GEMM1 + tanh -> sh_h ----
    for (int mt1 = 0; mt1 < PPB/16; ++mt1){
      const u16* irow = sin_cur + (size_t)(mt1*16 + m16) * 64;
      bf16x8 b0 = *(const bf16x8*)(irow + ((q ^ sw3) * 8));
      bf16x8 b1 = *(const bf16x8*)(irow + (((q + 4) ^ sw3) * 8));
      f32x4 acc = {0.f, 0.f, 0.f, 0.f};
      acc = __builtin_amdgcn_mfma_f32_16x16x32_bf16(af0, b0, acc, 0, 0, 0);
      acc = __builtin_amdgcn_mfma_f32_16x16x32_bf16(af1, b1, acc, 0, 0, 0);
      u32 lo = (u32)f2bf(tanh_fast(acc[0])) | ((u32)f2bf(tanh_fast(acc[1])) << 16);
      u32 hi = (u32)f2bf(tanh_fast(acc[2])) | ((u32)f2bf(tanh_fast(acc[3])) << 16);
      u32x2 pk = {lo, hi};
      *(u32x2*)(sh_h + (size_t)(mt1*16 + m16)*256 + cw*8 + (q & 1)*4) = pk;
    }
    __syncthreads();

    // ---- B: issue next-chunk p1-row loads (indices arrived during GEMM1) ----
    f32x4 gi0, gi1, gj0, gj1;
    if (pf){
      const float* si = p1 + (size_t)(u32)nxt_i*64 + seg_g*8;
      const float* sj = p1 + (size_t)(u32)nxt_j*64 + seg_g*8;
      gi0 = ((const f32x4*)si)[0]; gi1 = ((const f32x4*)si)[1];
      gj0 = ((const f32x4*)sj)[0]; gj1 = ((const f32x4*)sj)[1];
    }
    __builtin_amdgcn_sched_barrier(0);   // keep loads issued before GEMM2

    // ---- B: GEMM2 vs register W2, fold basis, stage to sh_out ----
    for (int mt = 0; mt < PPB/16; ++mt){
      const int row = mt*16 + m16;
      const int mg  = pb + row;
      const int mgc = (mg < n_pairs) ? mg : (n_pairs - 1);
      f32x4 bb = *(const f32x4*)(basis + (size_t)mgc*8 + (q & 1)*4);

      const u16* hbase = sh_h + (size_t)row * 256;
      f32x4 acc0 = {0.f, 0.f, 0.f, 0.f};
      f32x4 acc1 = {0.f, 0.f, 0.f, 0.f};

      bf16x8 bh = *(const bf16x8*)(hbase + ((q ^ m16) * 8));   // chunk kk=0
#pragma unroll
      for (int kk = 0; kk < 8; ++kk){
        bf16x8 bhn;
        if (kk < 7) bhn = *(const bf16x8*)(hbase + ((((kk + 1)*4 + q) ^ m16) * 8));
        acc0 = __builtin_amdgcn_mfma_f32_16x16x32_bf16(awf[kk][0], bh, acc0, 0, 0, 0);
        acc1 = __builtin_amdgcn_mfma_f32_16x16x32_bf16(awf[kk][1], bh, acc1, 0, 0, 0);
        bh = bhn;
      }

      // n = w*32 + nt*16 + q*4 + reg; c = w*4 + nt*2 + (q>>1); b = (q&1)*4 + reg
#pragma unroll
      for (int nt = 0; nt < 2; ++nt){
        f32x4 a = (nt == 0) ? acc0 : acc1;
        float s = a[0]*bb[0] + a[1]*bb[1] + a[2]*bb[2] + a[3]*bb[3];
        s += __shfl_xor(s, 16);          // sum b-halves (q0+q1 / q2+q3)
        float v2 = __shfl_xor(s, 32);    // partner c-channel
        if (q == 0){
          f32x2 pk = {s, v2};
          *(f32x2*)(sh_out + row*68 + w*4 + nt*2) = pk;  // 2-way bank = free
        }
      }
    }

    if (pf){   // convert + stage chunk t+1 into the other inter buffer
      u16x8 r;
#pragma unroll
      for (int e = 0; e < 4; ++e){
        r[e]     = f2bf(gi0[e] + gj0[e]);
        r[e + 4] = f2bf(gi1[e] + gj1[e]);
      }
      *(u16x8*)(sin_nxt + m_g*64 + ((seg_g ^ (m_g & 7)) * 8)) = r;
    }
    __syncthreads();
    u16* tmp = sin_cur; sin_cur = sin_nxt; sin_nxt = tmp;
  }

  // ---- Tail: drain the last chunk's staged output ----
  {
    const int mg = pbase + (CPB - 1)*PPB + m_g;
    if (mg < n_pairs){
      const float* src = sh_out + m_g*68 + seg_g*8;
      f32x4 v0 = *(const f32x4*)(src);
      f32x4 v1 = *(const f32x4*)(src + 4);
      float* dst = out + (size_t)mg*64 + seg_g*8;
      *(f32x4*)(dst)     = v0;
      *(f32x4*)(dst + 4) = v1;
    }
  }
}

extern "C" void kernel_launch(void* const* d_in, const int* in_sizes, int n_in,
                              void* d_out, int out_size, void* d_ws, size_t ws_size,
                              hipStream_t stream)
{
  const float* p1    = (const float*)d_in[0];
  const int*   pi    = (const int*)d_in[1];
  const int*   pj    = (const int*)d_in[2];
  const float* basis = (const float*)d_in[3];
  const float* W1    = (const float*)d_in[4];  // [64][256] f32
  const float* W2    = (const float*)d_in[5];  // [256][512] f32
  float* out = (float*)d_out;

  u16* w1t = (u16*)d_ws;                   // [256][64]   bf16 = 32 KB
  u16* w2b = w1t + 64 * 256;               // [8][512][32] bf16 = 256 KB

  const int n_pairs = in_sizes[1];
  const int lds_bytes = (PPB*256 + 2*PPB*64) * (int)sizeof(u16)
                      + PPB * 68 * (int)sizeof(float);   // 133120 B

  static int attr_done = 0;  // attribute is device-global state, not stream work;
  if (!attr_done){           // first (uncaptured) call sets it before capture
    hipFuncSetAttribute((const void*)pilayer_kernel,
                        hipFuncAttributeMaxDynamicSharedMemorySize, lds_bytes);
    attr_done = 1;
  }

  transpose_cast_k<<<dim3(4, 1), 256, 0, stream>>>(W1, w1t, 64, 256);
  w2_block_k<<<dim3(8, 8), 256, 0, stream>>>(W2, w2b);

  const int n_chunks = (n_pairs + PPB - 1) / PPB;
  const int blocks   = (n_chunks + CPB - 1) / CPB;
  pilayer_kernel<<<blocks, 1024, lds_bytes, stream>>>(
      p1, pi, pj, basis, w1t, w2b, out, n_pairs);
}